// Round 6
// baseline (599.161 us; speedup 1.0000x reference)
//
#include <hip/hip_runtime.h>
#include <stdint.h>

// Entmax-1.5 over last axis. tau* is the root of
//   f(tau) = sum_i max(x_i - tau, 0)^2 - 1   (convex, piecewise quadratic, decreasing)
// Rationalized Michelot iteration (exact root for current support set):
//   u = (F-1) / (G + sqrt(G^2 - K*(F-1))),  F = sum y^2, G = sum y, K = #{y>0}
//
// Round-5 finding (the plateau's cause): per-row VALU instr count (from VALUBusy
// arithmetic) = ~2170 packed instrs = ~16 solve iterations -- the |u| > 2e-7 stop
// rule NEVER fires because c = F-1 is catastrophically cancelled (F ~ 1, fp32
// noise ~1e-6 > 2e-7), so every row burns the full iteration cap. That serial
// ~24k cyc/row solve is why 5 different memory structures were all time-identical.
//
// Fix: terminate on SUPPORT-SET STABILITY (K == K_prev). K comes from
// ballot+popcount -> integer, bitwise wave-uniform, immune to fp noise. The tau
// update is already the exact closed-form root for the measured support, so when
// K repeats, tau is final (same formula the JAX reference evaluates at the chosen
// support size). Secondary loose break |u| <= 1e-6 (output err <= 2e-6 << tol).
// Michelot stabilizes in 2-5 iterations -> ~4x shorter serial solve per row.
//
// Memory structure unchanged from round 5 (GLDS DMA pipeline, counted vmcnt):
//   - global_load_lds width 16 stages row r+1 into per-wave 16 KiB LDS while
//     row r is solved from registers; compiler cannot sink a DMA.
//   - vmcnt(8) at iter top drains the 16 older GLDS without waiting on the 8
//     newer stores; vmcnt(0) only for r==0; lgkmcnt(0) before re-staging.

#define NEG_FILL (-1.0e4f)

typedef float float2v __attribute__((ext_vector_type(2)));

static constexpr int S_DIM = 2048;
static constexpr int WAVES_PER_BLOCK = 4;        // 256-thread blocks
static constexpr int ROWS_PER_WAVE = 8;          // grid = 32768/(4*8) = 1024 blocks
static constexpr int ELEMS = S_DIM / 64;         // 32 floats per lane per row
static constexpr int VEC = ELEMS / 4;            // 8 float4 chunks per lane per row
static constexpr int VEC2 = ELEMS / 2;           // 16 float2 chunks per lane per row
static constexpr int ROW_BYTES = S_DIM * 4;      // 8 KiB
static constexpr int WBUF_BYTES = 2 * ROW_BYTES; // 16 KiB per wave (scores+mask)

__global__ __launch_bounds__(256) void entmax15_kernel(
    const float* __restrict__ scores,
    const int*   __restrict__ mask,
    float*       __restrict__ out,
    int nrows)
{
    __shared__ char smem[WAVES_PER_BLOCK * WBUF_BYTES];  // 64 KiB

    const int lane = threadIdx.x & 63;
    const int wave = threadIdx.x >> 6;
    const int row0 = (blockIdx.x * WAVES_PER_BLOCK + wave) * ROWS_PER_WAVE;
    if (row0 >= nrows) return;

    char* wbuf = &smem[wave * WBUF_BYTES];
    const char* sbase = (const char*)scores;
    const char* mbase = (const char*)mask;

    // async-stage one row (scores 8 KiB + mask 8 KiB) into this wave's LDS buffer.
    // LDS dest is wave-uniform base + lane*16 (HW rule); global src is per-lane.
    auto stage = [&](int row) {
        const char* srow = sbase + (size_t)row * ROW_BYTES;
        const char* mrow = mbase + (size_t)row * ROW_BYTES;
#pragma unroll
        for (int j = 0; j < VEC; ++j) {
            __builtin_amdgcn_global_load_lds(
                (const __attribute__((address_space(1))) void*)(srow + lane * 16 + j * 1024),
                (__attribute__((address_space(3))) void*)(wbuf + j * 1024),
                16, 0, 0);
        }
#pragma unroll
        for (int j = 0; j < VEC; ++j) {
            __builtin_amdgcn_global_load_lds(
                (const __attribute__((address_space(1))) void*)(mrow + lane * 16 + j * 1024),
                (__attribute__((address_space(3))) void*)(wbuf + ROW_BYTES + j * 1024),
                16, 0, 0);
        }
    };

    // prologue: stage row0
    stage(row0);

    const float2v h05   = {0.5f, 0.5f};
    const float2v one2  = {1.0f, 1.0f};
    const float2v zero2 = {0.0f, 0.0f};

#pragma unroll 1
    for (int r = 0; r < ROWS_PER_WAVE; ++r) {
        const int row = row0 + r;
        if (row >= nrows) break;

        // ---- wait for this row's staged data.
        if (r == 0) {
            asm volatile("s_waitcnt vmcnt(0)" ::: "memory");
        } else {
            asm volatile("s_waitcnt vmcnt(8)" ::: "memory");
        }
        __builtin_amdgcn_sched_barrier(0);

        // ---- LDS -> regs: mask-select + row max ----
        const float4* __restrict__ sl = (const float4*)wbuf;
        const int4*   __restrict__ ml = (const int4*)(wbuf + ROW_BYTES);
        float x[ELEMS];
        float rmax = -3.402823466e38f;
#pragma unroll
        for (int j = 0; j < VEC; ++j) {
            const float4 s = sl[64 * j + lane];
            const int4   m = ml[64 * j + lane];
            float v0 = m.x ? s.x : NEG_FILL;
            float v1 = m.y ? s.y : NEG_FILL;
            float v2 = m.z ? s.z : NEG_FILL;
            float v3 = m.w ? s.w : NEG_FILL;
            x[4 * j + 0] = v0;
            x[4 * j + 1] = v1;
            x[4 * j + 2] = v2;
            x[4 * j + 3] = v3;
            rmax = fmaxf(rmax, fmaxf(fmaxf(v0, v1), fmaxf(v2, v3)));
        }
        // all ds_reads retired before the buffer is re-staged
        asm volatile("s_waitcnt lgkmcnt(0)" ::: "memory");
        __builtin_amdgcn_sched_barrier(0);

        // ---- issue next row's DMA now; it flies during the solve below ----
        if (r + 1 < ROWS_PER_WAVE && row + 1 < nrows)
            stage(row + 1);
        __builtin_amdgcn_sched_barrier(0);

        // ---- rmax butterfly ----
#pragma unroll
        for (int off = 32; off >= 1; off >>= 1)
            rmax = fmaxf(rmax, __shfl_xor(rmax, off, 64));

        // ---- alpha=1.5 transform fused with first exact step at tau0=-1 ----
        // x = (x - max)*0.5  =>  max(x)==0, tau* in [-1, 0).  At tau=-1: d = x+1.
        const float2v sh2 = {-0.5f * rmax, -0.5f * rmax};
        float2v* xv = (float2v*)x;

        float2v F2 = zero2, G2 = zero2;
        int K = 0;
#pragma unroll
        for (int i = 0; i < VEC2; ++i) {
            float2v t = __builtin_elementwise_fma(xv[i], h05, sh2);   // v_pk_fma_f32
            xv[i] = t;
            float2v d = t + one2;
            float2v y = __builtin_elementwise_max(d, zero2);
            F2 = __builtin_elementwise_fma(y, y, F2);
            G2 = G2 + y;
            K += __popcll(__ballot(d.x > 0.0f));
            K += __popcll(__ballot(d.y > 0.0f));
        }

        float2v FG;
        FG.x = F2.x + F2.y;
        FG.y = G2.x + G2.y;
#pragma unroll
        for (int off = 32; off >= 1; off >>= 1) {
            float2v t;
            t.x = __shfl_xor(FG.x, off, 64);
            t.y = __shfl_xor(FG.y, off, 64);
            FG += t;
        }

        float c     = FG.x - 1.0f;                     // F - 1 (>= 0 from below)
        float disc  = fmaf(FG.y, FG.y, -(float)K * c); // G^2 - K*(F-1)
        float denom = (disc > 0.0f) ? (FG.y + sqrtf(disc)) : (2.0f * FG.y);
        float u     = c / denom;
        float tau   = -1.0f + u;
        int   Kprev = K;

        // ---- remaining iterations: stop on SUPPORT STABILITY (K == Kprev).
        // K is integer + bitwise wave-uniform (ballot/popc) -> exact stop rule;
        // the tau update is the exact root for the measured support, so a
        // repeated K means tau is final. Loose |u| break as secondary guard.
#pragma unroll 1
        for (int it = 1; it < 16; ++it) {
            const float2v t2 = {tau, tau};
            F2 = zero2; G2 = zero2; K = 0;
#pragma unroll
            for (int i = 0; i < VEC2; ++i) {
                float2v d = xv[i] - t2;
                float2v y = __builtin_elementwise_max(d, zero2);
                F2 = __builtin_elementwise_fma(y, y, F2);
                G2 = G2 + y;
                K += __popcll(__ballot(d.x > 0.0f));
                K += __popcll(__ballot(d.y > 0.0f));
            }
            FG.x = F2.x + F2.y;
            FG.y = G2.x + G2.y;
#pragma unroll
            for (int off = 32; off >= 1; off >>= 1) {
                float2v t;
                t.x = __shfl_xor(FG.x, off, 64);
                t.y = __shfl_xor(FG.y, off, 64);
                FG += t;
            }
            c     = FG.x - 1.0f;
            disc  = fmaf(FG.y, FG.y, -(float)K * c);
            denom = (disc > 0.0f) ? (FG.y + sqrtf(disc)) : (2.0f * FG.y);
            u     = c / denom;
            tau  += u;
            if (K == Kprev || !(fabsf(u) > 1e-6f)) break;
            Kprev = K;
        }

        // ---- epilogue: p = max(x - tau, 0)^2, 8x global_store_dwordx4 ----
        float4* __restrict__ orow = (float4*)(out + (size_t)row * S_DIM);
        const float2v t2 = {tau, tau};
#pragma unroll
        for (int j = 0; j < VEC; ++j) {
            float2v y0 = __builtin_elementwise_max(xv[2 * j]     - t2, zero2);
            float2v y1 = __builtin_elementwise_max(xv[2 * j + 1] - t2, zero2);
            float2v o0 = y0 * y0;
            float2v o1 = y1 * y1;
            float4 o;
            o.x = o0.x; o.y = o0.y; o.z = o1.x; o.w = o1.y;
            orow[64 * j + lane] = o;
        }
    }
}

extern "C" void kernel_launch(void* const* d_in, const int* in_sizes, int n_in,
                              void* d_out, int out_size, void* d_ws, size_t ws_size,
                              hipStream_t stream) {
    const float* scores = (const float*)d_in[0];
    const int*   mask   = (const int*)d_in[1];
    float*       out    = (float*)d_out;

    const int nrows = in_sizes[0] / S_DIM;  // 32768
    const int rows_per_block = WAVES_PER_BLOCK * ROWS_PER_WAVE;
    const int grid = (nrows + rows_per_block - 1) / rows_per_block;

    entmax15_kernel<<<grid, 256, 0, stream>>>(scores, mask, out, nrows);
}

// Round 8
// 593.863 us; speedup vs baseline: 1.0089x; 1.0089x over previous
//
#include <hip/hip_runtime.h>
#include <stdint.h>

// Entmax-1.5 over last axis. tau* is the root of
//   f(tau) = sum_i max(x_i - tau, 0)^2 - 1   (convex, piecewise quadratic, decreasing)
// Rationalized Michelot iteration (exact root for current support set):
//   u = (F-1) / (G + sqrt(G^2 - K*(F-1))),  F = sum y^2, G = sum y, K = #{y>0}
//
// Round-7 analysis: ALL passing structures (R0/R2/R3/R5/R6) ran at the same
// app-level memory service rate, 6.3 +/- 0.2 B/cyc/CU (~3.9 TB/s), across
// occupancies 19-45% and three memory paths. The kernel has been rate-limited
// since round 0; overlap attempts were correctly null. Known-good streaming
// kernels on MI355X reach ~5 TB/s -- but as fine-grained high-occupancy
// streamers, not 16 KiB-burst-then-silent waves.
//
// Round-8 test: BLOCK-PER-ROW fine-grained streaming.
//   - one 256-thread block per row; 8 elems/thread (2 float4 + 2 int4 loads).
//   - ~40 VGPR, 128 B LDS -> 8 blocks/CU resident = 32 waves/CU (4x more than
//     R5/R6), each issuing small requests at fine grain: smoothest request
//     stream this problem admits.
//   - cross-wave reduction: wave butterfly -> lane0 writes {F,G,K} partial to
//     parity-double-buffered LDS -> one barrier -> every thread sums 4 partials
//     (broadcast reads). One __syncthreads per iteration.
// Kept: packed-fp32 math, ballot+popc K (wave-total for free), fused first
// step, K-stability stop (integer, block-uniform from identical LDS values).

#define NEG_FILL (-1.0e4f)

typedef float float2v __attribute__((ext_vector_type(2)));

static constexpr int S_DIM   = 2048;
static constexpr int THREADS = 256;
static constexpr int NWAVES  = THREADS / 64;    // 4 waves per block
static constexpr int EPT     = S_DIM / THREADS; // 8 elements per thread
static constexpr int V2      = EPT / 2;         // 4 float2 chunks per thread

__global__ __launch_bounds__(THREADS) void entmax15_kernel(
    const float* __restrict__ scores,
    const int*   __restrict__ mask,
    float*       __restrict__ out,
    int nrows)
{
    __shared__ float red[2][NWAVES][4];  // [parity][wave][{F,G,K,pad}]

    const int tid  = threadIdx.x;
    const int lane = tid & 63;
    const int wv   = tid >> 6;
    const int row  = blockIdx.x;
    if (row >= nrows) return;

    const size_t base = (size_t)row * S_DIM;
    const float4* __restrict__ srow = (const float4*)(scores + base);
    const int4*   __restrict__ mrow = (const int4*)(mask + base);
    float4*       __restrict__ orow = (float4*)(out + base);

    // ---- coalesced load: thread t owns float4 chunks t and t+256 ----
    const float4 sa = srow[tid];
    const float4 sb = srow[tid + THREADS];
    const int4   ma = mrow[tid];
    const int4   mb = mrow[tid + THREADS];

    float x[EPT];
    x[0] = ma.x ? sa.x : NEG_FILL;
    x[1] = ma.y ? sa.y : NEG_FILL;
    x[2] = ma.z ? sa.z : NEG_FILL;
    x[3] = ma.w ? sa.w : NEG_FILL;
    x[4] = mb.x ? sb.x : NEG_FILL;
    x[5] = mb.y ? sb.y : NEG_FILL;
    x[6] = mb.z ? sb.z : NEG_FILL;
    x[7] = mb.w ? sb.w : NEG_FILL;

    // ---- row max: thread -> wave butterfly -> cross-wave via LDS ----
    float rmax = fmaxf(fmaxf(fmaxf(x[0], x[1]), fmaxf(x[2], x[3])),
                       fmaxf(fmaxf(x[4], x[5]), fmaxf(x[6], x[7])));
#pragma unroll
    for (int off = 32; off >= 1; off >>= 1)
        rmax = fmaxf(rmax, __shfl_xor(rmax, off, 64));
    if (lane == 0) red[0][wv][0] = rmax;
    __syncthreads();
    rmax = fmaxf(fmaxf(red[0][0][0], red[0][1][0]),
                 fmaxf(red[0][2][0], red[0][3][0]));

    // ---- alpha=1.5 transform fused with first exact step at tau0=-1 ----
    // x = (x - max)*0.5  =>  max(x)==0, tau* in [-1, 0).  At tau=-1: d = x+1.
    const float2v h05   = {0.5f, 0.5f};
    const float2v one2  = {1.0f, 1.0f};
    const float2v zero2 = {0.0f, 0.0f};
    const float2v sh2   = {-0.5f * rmax, -0.5f * rmax};
    float2v* xv = (float2v*)x;

    float2v F2 = zero2, G2 = zero2;
    int Kw = 0;
#pragma unroll
    for (int i = 0; i < V2; ++i) {
        float2v t = __builtin_elementwise_fma(xv[i], h05, sh2);   // v_pk_fma_f32
        xv[i] = t;
        float2v d = t + one2;
        float2v y = __builtin_elementwise_max(d, zero2);
        F2 = __builtin_elementwise_fma(y, y, F2);
        G2 = G2 + y;
        Kw += __popcll(__ballot(d.x > 0.0f));   // wave-total count, SALU
        Kw += __popcll(__ballot(d.y > 0.0f));
    }
    float2v FG;
    FG.x = F2.x + F2.y;
    FG.y = G2.x + G2.y;
#pragma unroll
    for (int off = 32; off >= 1; off >>= 1) {
        float2v t;
        t.x = __shfl_xor(FG.x, off, 64);
        t.y = __shfl_xor(FG.y, off, 64);
        FG += t;
    }
    if (lane == 0) {
        red[1][wv][0] = FG.x;
        red[1][wv][1] = FG.y;
        red[1][wv][2] = (float)Kw;
    }
    __syncthreads();
    float F  = red[1][0][0] + red[1][1][0] + red[1][2][0] + red[1][3][0];
    float G  = red[1][0][1] + red[1][1][1] + red[1][2][1] + red[1][3][1];
    float Kf = red[1][0][2] + red[1][1][2] + red[1][2][2] + red[1][3][2];
    int   K  = (int)Kf;

    float c     = F - 1.0f;                    // F - 1 (>= 0 from below)
    float disc  = fmaf(G, G, -Kf * c);         // G^2 - K*(F-1)
    float denom = (disc > 0.0f) ? (G + sqrtf(disc)) : (2.0f * G);
    float u     = c / denom;
    float tau   = -1.0f + u;
    int   Kprev = K;

    // ---- remaining iterations: stop on support stability (K == Kprev) or
    // loose |u| <= 1e-6. All values block-uniform (identical LDS sums) ->
    // uniform branch. Parity double-buffer -> one barrier per iteration.
#pragma unroll 1
    for (int it = 1; it < 16; ++it) {
        const float2v t2 = {tau, tau};
        F2 = zero2; G2 = zero2; Kw = 0;
#pragma unroll
        for (int i = 0; i < V2; ++i) {
            float2v d = xv[i] - t2;
            float2v y = __builtin_elementwise_max(d, zero2);
            F2 = __builtin_elementwise_fma(y, y, F2);
            G2 = G2 + y;
            Kw += __popcll(__ballot(d.x > 0.0f));
            Kw += __popcll(__ballot(d.y > 0.0f));
        }
        FG.x = F2.x + F2.y;
        FG.y = G2.x + G2.y;
#pragma unroll
        for (int off = 32; off >= 1; off >>= 1) {
            float2v t;
            t.x = __shfl_xor(FG.x, off, 64);
            t.y = __shfl_xor(FG.y, off, 64);
            FG += t;
        }
        const int slot = (it & 1) ^ 1;   // it=1 -> slot0 (rmax slot, long since read)
        if (lane == 0) {
            red[slot][wv][0] = FG.x;
            red[slot][wv][1] = FG.y;
            red[slot][wv][2] = (float)Kw;
        }
        __syncthreads();
        F  = red[slot][0][0] + red[slot][1][0] + red[slot][2][0] + red[slot][3][0];
        G  = red[slot][0][1] + red[slot][1][1] + red[slot][2][1] + red[slot][3][1];
        Kf = red[slot][0][2] + red[slot][1][2] + red[slot][2][2] + red[slot][3][2];
        K  = (int)Kf;

        c     = F - 1.0f;
        disc  = fmaf(G, G, -Kf * c);
        denom = (disc > 0.0f) ? (G + sqrtf(disc)) : (2.0f * G);
        u     = c / denom;
        tau  += u;
        if (K == Kprev || !(fabsf(u) > 1e-6f)) break;
        Kprev = K;
    }

    // ---- epilogue: p = max(x - tau, 0)^2, 2 coalesced float4 stores ----
    const float2v t2 = {tau, tau};
    float2v o0 = __builtin_elementwise_max(xv[0] - t2, zero2);
    float2v o1 = __builtin_elementwise_max(xv[1] - t2, zero2);
    float2v o2 = __builtin_elementwise_max(xv[2] - t2, zero2);
    float2v o3 = __builtin_elementwise_max(xv[3] - t2, zero2);
    o0 = o0 * o0;
    o1 = o1 * o1;
    o2 = o2 * o2;
    o3 = o3 * o3;
    float4 oa, ob;
    oa.x = o0.x; oa.y = o0.y; oa.z = o1.x; oa.w = o1.y;
    ob.x = o2.x; ob.y = o2.y; ob.z = o3.x; ob.w = o3.y;
    orow[tid]           = oa;
    orow[tid + THREADS] = ob;
}

extern "C" void kernel_launch(void* const* d_in, const int* in_sizes, int n_in,
                              void* d_out, int out_size, void* d_ws, size_t ws_size,
                              hipStream_t stream) {
    const float* scores = (const float*)d_in[0];
    const int*   mask   = (const int*)d_in[1];
    float*       out    = (float*)d_out;

    const int nrows = in_sizes[0] / S_DIM;  // 32768
    entmax15_kernel<<<nrows, THREADS, 0, stream>>>(scores, mask, out, nrows);
}